// Round 3
// baseline (795.373 us; speedup 1.0000x reference)
//
#include <hip/hip_runtime.h>
#include <hip/hip_bf16.h>
#include <stdint.h>

#define N_NODES 20000
#define E_EDGES 320000
#define IN_F    128
#define HIDF    256
#define R_REL   4
#define NRKEYS  (N_NODES*R_REL)   // 80000

typedef __attribute__((ext_vector_type(8))) short  short8;
typedef __attribute__((ext_vector_type(4))) float  floatx4;

__device__ __forceinline__ float bf2f(__hip_bfloat16 v){ return __bfloat162float(v); }
__device__ __forceinline__ __hip_bfloat16 f2bf(float v){ return __float2bfloat16(v); }

// ---------------- CSR build ----------------
__global__ void count_kernel(const int* __restrict__ ei, const int* __restrict__ et,
                             int* __restrict__ cnt)
{
    int e = blockIdx.x*256 + threadIdx.x;
    if (e >= E_EDGES) return;
    int dst = ei[E_EDGES + e];
    atomicAdd(&cnt[dst*R_REL + et[e]], 1);
}

__global__ __launch_bounds__(1024) void scan_kernel(const int* __restrict__ cnt,
                                                    int* __restrict__ row_ptr,
                                                    int* __restrict__ cursor)
{
    __shared__ int sums[1024];
    const int CH = (NRKEYS + 1023)/1024;  // 79
    int t = threadIdx.x;
    int base = t*CH;
    int s = 0;
    for (int j=0;j<CH;j++){ int ix=base+j; if (ix<NRKEYS) s += cnt[ix]; }
    sums[t] = s; __syncthreads();
    for (int off=1; off<1024; off<<=1) {
        int v = (t>=off)? sums[t-off] : 0;
        __syncthreads();
        sums[t] += v;
        __syncthreads();
    }
    int prefix = (t>0)? sums[t-1] : 0;
    for (int j=0;j<CH;j++){
        int ix = base+j;
        if (ix < NRKEYS){ row_ptr[ix]=prefix; cursor[ix]=prefix; prefix += cnt[ix]; }
    }
    if (t==1023) row_ptr[NRKEYS] = prefix;
}

__global__ void fill_kernel(const int* __restrict__ ei, const int* __restrict__ et,
                            int* __restrict__ cursor, int* __restrict__ csr_src)
{
    int e = blockIdx.x*256 + threadIdx.x;
    if (e >= E_EDGES) return;
    int src = ei[e];
    int dst = ei[E_EDGES + e];
    int key = dst*R_REL + et[e];
    int pos = atomicAdd(&cursor[key], 1);
    csr_src[pos] = src;
}

// ---------------- weight prep: fp32 sources -> bf16 B^T = [Nout][K] ----------------
__global__ void make_b1t(const float* __restrict__ root1,
                         const float* __restrict__ W1,
                         __hip_bfloat16* __restrict__ B1t)
{
    int idx = blockIdx.x*256 + threadIdx.x;         // n*640 + k
    if (idx >= 256*640) return;
    int n = idx / 640, k = idx % 640;
    float v;
    if (k < 128) v = root1[k*256 + n];
    else         v = W1[(k-128)*256 + n];           // W1 contiguous [R*128][256]
    B1t[idx] = f2bf(v);
}

__global__ void make_b2t(const float* __restrict__ root2,
                         const float* __restrict__ W2,
                         __hip_bfloat16* __restrict__ B2t)
{
    int idx = blockIdx.x*256 + threadIdx.x;         // n*1280 + k
    if (idx >= 256*1280) return;
    int n = idx / 1280, k = idx % 1280;
    float v;
    if (k < 256) v = root2[k*256 + n];
    else         v = W2[(k-256)*256 + n];           // W2 contiguous [R*256][256]
    B2t[idx] = f2bf(v);
}

__global__ void make_b3t(const float* __restrict__ Wq, const float* __restrict__ Wk,
                         const float* __restrict__ Wv, const float* __restrict__ Wsk,
                         const float* __restrict__ bq, const float* __restrict__ bk,
                         const float* __restrict__ bv, const float* __restrict__ bsk,
                         __hip_bfloat16* __restrict__ B3t, float* __restrict__ bias3)
{
    int idx = blockIdx.x*256 + threadIdx.x;         // n*256 + k, n<1024
    if (idx >= 1024*256) return;
    int n = idx / 256, k = idx % 256;
    int g = n >> 8, nn = n & 255;
    const float* W = (g==0)?Wq:(g==1)?Wk:(g==2)?Wv:Wsk;
    B3t[idx] = f2bf(W[k*256 + nn]);
    if (k == 0) {
        const float* B = (g==0)?bq:(g==1)?bk:(g==2)?bv:bsk;
        bias3[n] = B[nn];
    }
}

// generic fp32 -> bf16 elementwise convert (layout-preserving)
__global__ void cvt_f32_bf16(const float* __restrict__ in, __hip_bfloat16* __restrict__ out, int n)
{
    int i = blockIdx.x*256 + threadIdx.x;
    if (i < n) out[i] = f2bf(in[i]);
}

// ---------------- RGCN aggregation (gather, no atomics) ----------------
__global__ __launch_bounds__(128) void agg1_kernel(const float* __restrict__ x,
                                                   const int* __restrict__ row_ptr,
                                                   const int* __restrict__ csr_src,
                                                   __hip_bfloat16* __restrict__ A1)
{
    int b = blockIdx.x;           // i*4 + r
    int i = b >> 2, r = b & 3;
    int f = threadIdx.x;          // 0..127
    int e0 = row_ptr[b], e1 = row_ptr[b+1];
    float s = 0.f;
    for (int e=e0; e<e1; e++) {
        int sidx = csr_src[e];
        s += x[(size_t)sidx*IN_F + f];
    }
    float inv = (e1>e0) ? 1.f/(float)(e1-e0) : 0.f;
    A1[(size_t)i*640 + 128 + r*128 + f] = f2bf(s*inv);
    if (r == 0) A1[(size_t)i*640 + f] = f2bf(x[(size_t)i*IN_F + f]);
}

__global__ __launch_bounds__(256) void agg2_kernel(const int* __restrict__ row_ptr,
                                                   const int* __restrict__ csr_src,
                                                   __hip_bfloat16* __restrict__ A2)
{
    int b = blockIdx.x;
    int i = b >> 2, r = b & 3;
    int f = threadIdx.x;          // 0..255
    int e0 = row_ptr[b], e1 = row_ptr[b+1];
    float s = 0.f;
    for (int e=e0; e<e1; e++) {
        int sidx = csr_src[e];
        s += bf2f(A2[(size_t)sidx*1280 + f]);   // cols 0..255 hold h1
    }
    float inv = (e1>e0) ? 1.f/(float)(e1-e0) : 0.f;
    A2[(size_t)i*1280 + 256 + r*256 + f] = f2bf(s*inv);
}

// ---------------- MFMA GEMM: C[M x Nout] = act(A[M x K] * Bt[Nout x K]^T + bias) ----------------
__global__ __launch_bounds__(256) void gemm_bt(const __hip_bfloat16* __restrict__ A, int lda,
                                               const __hip_bfloat16* __restrict__ Bt,
                                               const float* __restrict__ bias,
                                               __hip_bfloat16* __restrict__ C, int ldc,
                                               int M, int K, int relu)
{
    __shared__ __align__(16) __hip_bfloat16 lds_a[128*32];
    __shared__ __align__(16) __hip_bfloat16 lds_b[128*32];
    const int tid    = threadIdx.x;
    const int tile_m = blockIdx.x * 128;
    const int tile_n = blockIdx.y * 128;
    const int wave   = tid >> 6;
    const int lane   = tid & 63;
    const int wm = wave >> 1, wn = wave & 1;     // 2x2 wave grid: 64x64 each
    const int fm = lane & 15;                    // frag m (A) / n (Bt) / col (C)
    const int q  = lane >> 4;                    // 0..3

    floatx4 acc[4][4];
    #pragma unroll
    for (int i=0;i<4;i++)
        #pragma unroll
        for (int j=0;j<4;j++) acc[i][j] = (floatx4){0.f,0.f,0.f,0.f};

    const int srow   = tid >> 2;                 // 0..63 (plus 64 per pass)
    const int schunk = (tid & 3) * 8;            // element offset along K

    for (int k0 = 0; k0 < K; k0 += 32) {
        __syncthreads();
        #pragma unroll
        for (int p=0;p<2;p++) {
            int row = p*64 + srow;
            int ga  = min(tile_m + row, M-1);    // clamp: pad rows read row M-1 (discarded)
            uint4 v = *(const uint4*)(A + (size_t)ga*lda + k0 + schunk);
            *(uint4*)(&lds_a[row*32 + schunk]) = v;
        }
        #pragma unroll
        for (int p=0;p<2;p++) {
            int row = p*64 + srow;
            uint4 v = *(const uint4*)(Bt + (size_t)(tile_n + row)*K + k0 + schunk);
            *(uint4*)(&lds_b[row*32 + schunk]) = v;
        }
        __syncthreads();

        short8 afr[4], bfr[4];
        #pragma unroll
        for (int i=0;i<4;i++) {
            afr[i] = *(const short8*)(&lds_a[(wm*64 + i*16 + fm)*32 + q*8]);
            bfr[i] = *(const short8*)(&lds_b[(wn*64 + i*16 + fm)*32 + q*8]);
        }
        #pragma unroll
        for (int i=0;i<4;i++)
            #pragma unroll
            for (int j=0;j<4;j++)
                acc[i][j] = __builtin_amdgcn_mfma_f32_16x16x32_bf16(afr[i], bfr[j], acc[i][j], 0,0,0);
    }

    const int crow_base = tile_m + wm*64;
    const int ccol_base = tile_n + wn*64;
    #pragma unroll
    for (int i=0;i<4;i++) {
        #pragma unroll
        for (int j=0;j<4;j++) {
            int c  = ccol_base + j*16 + fm;
            float bb = bias[c];
            #pragma unroll
            for (int rg=0; rg<4; rg++) {
                int r = crow_base + i*16 + q*4 + rg;
                if (r < M) {
                    float v = acc[i][j][rg] + bb;
                    if (relu) v = fmaxf(v, 0.f);
                    C[(size_t)r*ldc + c] = f2bf(v);
                }
            }
        }
    }
}

// ---------------- TransformerConv attention (one block/node, one wave/head) ----------------
__global__ __launch_bounds__(256) void attn_kernel(const __hip_bfloat16* __restrict__ qkvs,
                                                   const int* __restrict__ row_ptr,
                                                   const int* __restrict__ csr_src,
                                                   __hip_bfloat16* __restrict__ hatt)
{
    int i = blockIdx.x;
    int h = threadIdx.x >> 6;
    int l = threadIdx.x & 63;
    const __hip_bfloat16* qrow = qkvs + (size_t)i*1024;
    float ql = bf2f(qrow[h*64 + l]);
    int e0 = row_ptr[i*R_REL], e1 = row_ptr[i*R_REL + R_REL];
    float m = -1e30f, ssum = 0.f, acc = 0.f;
    for (int e=e0; e<e1; e++) {
        int s = csr_src[e];
        const __hip_bfloat16* kv = qkvs + (size_t)s*1024;
        float kl = bf2f(kv[256 + h*64 + l]);
        float d = ql*kl;
        #pragma unroll
        for (int o=32;o>0;o>>=1) d += __shfl_xor(d, o, 64);
        float sc = d * 0.125f;                 // 1/sqrt(64)
        float mn = fmaxf(m, sc);
        float corr = __expf(m - mn);
        float p    = __expf(sc - mn);
        ssum = ssum*corr + p;
        float vl = bf2f(kv[512 + h*64 + l]);
        acc = acc*corr + p*vl;
        m = mn;
    }
    float o = acc / fmaxf(ssum, 1e-16f);
    float skip = bf2f(qrow[768 + h*64 + l]);
    hatt[(size_t)i*256 + h*64 + l] = f2bf(o + skip);
}

// ---------------- GRU elementwise (bf16 gates, fp32 math, fp32 out) ----------------
__global__ void gru_kernel(const __hip_bfloat16* __restrict__ gi,
                           const __hip_bfloat16* __restrict__ gh,
                           const float* __restrict__ hprev,
                           float* __restrict__ out)
{
    int idx = blockIdx.x*256 + threadIdx.x;
    if (idx >= N_NODES*HIDF) return;
    int i = idx / HIDF, c = idx % HIDF;
    size_t gb = (size_t)i*768;
    float ir = bf2f(gi[gb + c]), iz = bf2f(gi[gb + 256 + c]), in = bf2f(gi[gb + 512 + c]);
    float hr = bf2f(gh[gb + c]), hz = bf2f(gh[gb + 256 + c]), hn = bf2f(gh[gb + 512 + c]);
    float r = 1.f/(1.f + __expf(-(ir+hr)));
    float z = 1.f/(1.f + __expf(-(iz+hz)));
    float n = tanhf(in + r*hn);
    float h = hprev[idx];
    out[idx] = (1.f - z)*n + z*h;
}

// ---------------- launch ----------------
// Inputs are fp32 per the reference (jnp.float32 everywhere); convert to bf16
// for MFMA. Workspace aliasing (lifetime-based), ~96 MB:
//   P1 (30.72 MB): A1 -> h2 -> hatt -> gh
//   P2 (51.2  MB): A2 -> qkvs -> gi
// Ordering: gemm4 (reads hatt, writes gi) BEFORE gemm5 (writes gh over hatt).
extern "C" void kernel_launch(void* const* d_in, const int* in_sizes, int n_in,
                              void* d_out, int out_size, void* d_ws, size_t ws_size,
                              hipStream_t stream)
{
    const float* x       = (const float*)d_in[0];
    const int* edge_index= (const int*)d_in[1];
    const int* edge_type = (const int*)d_in[2];
    const float* hprev   = (const float*)d_in[3];
    const float* W1      = (const float*)d_in[4];
    const float* root1   = (const float*)d_in[5];
    const float* b1      = (const float*)d_in[6];
    const float* W2      = (const float*)d_in[7];
    const float* root2   = (const float*)d_in[8];
    const float* b2      = (const float*)d_in[9];
    const float* Wq      = (const float*)d_in[10];
    const float* bq      = (const float*)d_in[11];
    const float* Wk      = (const float*)d_in[12];
    const float* bk      = (const float*)d_in[13];
    const float* Wv      = (const float*)d_in[14];
    const float* bv      = (const float*)d_in[15];
    const float* Wskip   = (const float*)d_in[16];
    const float* bskip   = (const float*)d_in[17];
    const float* W_ih    = (const float*)d_in[18];
    const float* b_ih    = (const float*)d_in[19];
    const float* W_hh    = (const float*)d_in[20];
    const float* b_hh    = (const float*)d_in[21];

    char* ws = (char*)d_ws;
    size_t off = 0;
    auto take = [&](size_t bytes)->char* {
        char* p = ws + off;
        off = (off + bytes + 255) & ~(size_t)255;
        return p;
    };
    int* cnt        = (int*)take((size_t)NRKEYS*4);
    int* row_ptr    = (int*)take((size_t)(NRKEYS+1)*4);
    int* cursor     = (int*)take((size_t)NRKEYS*4);
    int* csr_src    = (int*)take((size_t)E_EDGES*4);
    __hip_bfloat16* B1t   = (__hip_bfloat16*)take((size_t)256*640*2);
    __hip_bfloat16* B2t   = (__hip_bfloat16*)take((size_t)256*1280*2);
    __hip_bfloat16* B3t   = (__hip_bfloat16*)take((size_t)1024*256*2);
    __hip_bfloat16* Biht  = (__hip_bfloat16*)take((size_t)768*256*2);
    __hip_bfloat16* Bhht  = (__hip_bfloat16*)take((size_t)768*256*2);
    float*          bias3 = (float*)take((size_t)1024*4);
    __hip_bfloat16* hprev_bf = (__hip_bfloat16*)take((size_t)N_NODES*256*2);
    // P1: max(A1 N*640, h2 N*256, hatt N*256, gh N*768) bf16
    char* P1 = take((size_t)N_NODES*768*2);
    // P2: max(A2 N*1280, qkvs N*1024, gi N*768) bf16
    char* P2 = take((size_t)N_NODES*1280*2);

    __hip_bfloat16* A1   = (__hip_bfloat16*)P1;   // [N,640]  dead after gemm1
    __hip_bfloat16* h2   = (__hip_bfloat16*)P1;   // [N,256]  dead after gemm3
    __hip_bfloat16* hatt = (__hip_bfloat16*)P1;   // [N,256]  dead after gemm4
    __hip_bfloat16* gh   = (__hip_bfloat16*)P1;   // [N,768]  written gemm5
    __hip_bfloat16* A2   = (__hip_bfloat16*)P2;   // [N,1280] dead after gemm2
    __hip_bfloat16* qkvs = (__hip_bfloat16*)P2;   // [N,1024] dead after attn
    __hip_bfloat16* gi   = (__hip_bfloat16*)P2;   // [N,768]  written gemm4

    hipMemsetAsync(cnt, 0, (size_t)NRKEYS*4, stream);
    count_kernel<<<(E_EDGES+255)/256, 256, 0, stream>>>(edge_index, edge_type, cnt);
    scan_kernel<<<1, 1024, 0, stream>>>(cnt, row_ptr, cursor);
    fill_kernel<<<(E_EDGES+255)/256, 256, 0, stream>>>(edge_index, edge_type, cursor, csr_src);

    make_b1t<<<(256*640+255)/256, 256, 0, stream>>>(root1, W1, B1t);
    make_b2t<<<(256*1280+255)/256, 256, 0, stream>>>(root2, W2, B2t);
    make_b3t<<<(1024*256+255)/256, 256, 0, stream>>>(Wq, Wk, Wv, Wskip, bq, bk, bv, bskip, B3t, bias3);
    cvt_f32_bf16<<<(768*256+255)/256, 256, 0, stream>>>(W_ih, Biht, 768*256);
    cvt_f32_bf16<<<(768*256+255)/256, 256, 0, stream>>>(W_hh, Bhht, 768*256);
    cvt_f32_bf16<<<(N_NODES*256+255)/256, 256, 0, stream>>>(hprev, hprev_bf, N_NODES*256);

    agg1_kernel<<<NRKEYS, 128, 0, stream>>>(x, row_ptr, csr_src, A1);

    dim3 g12(157, 2);
    // h1 = relu(A1 * B1) written into A2 cols 0..255 (ldc=1280)
    gemm_bt<<<g12, 256, 0, stream>>>(A1, 640, B1t, b1, A2, 1280, N_NODES, 640, 1);

    agg2_kernel<<<NRKEYS, 256, 0, stream>>>(row_ptr, csr_src, A2);

    // h2 overwrites A1 (dead) in P1
    gemm_bt<<<g12, 256, 0, stream>>>(A2, 1280, B2t, b2, h2, 256, N_NODES, 1280, 1);

    // qkvs overwrites A2 (dead) in P2
    dim3 g3(157, 8);
    gemm_bt<<<g3, 256, 0, stream>>>(h2, 256, B3t, bias3, qkvs, 1024, N_NODES, 256, 0);

    // hatt overwrites h2 (dead) in P1
    attn_kernel<<<N_NODES, 256, 0, stream>>>(qkvs, row_ptr, csr_src, hatt);

    dim3 g45(157, 6);
    // gi overwrites qkvs (dead) in P2 -- must run before gemm5
    gemm_bt<<<g45, 256, 0, stream>>>(hatt,     256, Biht, b_ih, gi, 768, N_NODES, 256, 0);
    // gh overwrites hatt (dead) in P1
    gemm_bt<<<g45, 256, 0, stream>>>(hprev_bf, 256, Bhht, b_hh, gh, 768, N_NODES, 256, 0);

    gru_kernel<<<(N_NODES*HIDF+255)/256, 256, 0, stream>>>(gi, gh, hprev, (float*)d_out);
}

// Round 4
// 602.738 us; speedup vs baseline: 1.3196x; 1.3196x over previous
//
#include <hip/hip_runtime.h>
#include <hip/hip_bf16.h>
#include <stdint.h>

#define N_NODES 20000
#define E_EDGES 320000
#define IN_F    128
#define HIDF    256
#define R_REL   4
#define NRKEYS  (N_NODES*R_REL)   // 80000
#define SCAN_BLOCKS 80            // 80*1024 = 81920 >= NRKEYS

typedef __attribute__((ext_vector_type(8))) short  short8;
typedef __attribute__((ext_vector_type(4))) float  floatx4;

__device__ __forceinline__ float bf2f(__hip_bfloat16 v){ return __bfloat162float(v); }
__device__ __forceinline__ __hip_bfloat16 f2bf(float v){ return __float2bfloat16(v); }

// ---------------- CSR build ----------------
__global__ void count_kernel(const int* __restrict__ ei, const int* __restrict__ et,
                             int* __restrict__ cnt)
{
    int e = blockIdx.x*256 + threadIdx.x;
    if (e >= E_EDGES) return;
    int dst = ei[E_EDGES + e];
    atomicAdd(&cnt[dst*R_REL + et[e]], 1);
}

// 3-phase parallel exclusive scan over cnt[NRKEYS] -> row_ptr, cursor
__global__ __launch_bounds__(1024) void scan_reduce_kernel(const int* __restrict__ cnt,
                                                           int* __restrict__ blocksum)
{
    int ix = blockIdx.x*1024 + threadIdx.x;
    int v = (ix < NRKEYS) ? cnt[ix] : 0;
    #pragma unroll
    for (int o=32;o>0;o>>=1) v += __shfl_xor(v, o, 64);
    __shared__ int wsum[16];
    int wave = threadIdx.x >> 6, lane = threadIdx.x & 63;
    if (lane == 0) wsum[wave] = v;
    __syncthreads();
    if (threadIdx.x == 0) {
        int s = 0;
        #pragma unroll
        for (int w=0;w<16;w++) s += wsum[w];
        blocksum[blockIdx.x] = s;
    }
}

__global__ __launch_bounds__(128) void scan_sums_kernel(const int* __restrict__ blocksum,
                                                        int* __restrict__ blockoff)
{
    __shared__ int s[128];
    int t = threadIdx.x;
    int v = (t < SCAN_BLOCKS) ? blocksum[t] : 0;
    s[t] = v; __syncthreads();
    for (int off=1; off<128; off<<=1) {
        int u = (t>=off) ? s[t-off] : 0;
        __syncthreads();
        s[t] += u;
        __syncthreads();
    }
    if (t < SCAN_BLOCKS) blockoff[t] = s[t] - v;   // exclusive
}

__global__ __launch_bounds__(1024) void scan_apply_kernel(const int* __restrict__ cnt,
                                                          const int* __restrict__ blockoff,
                                                          int* __restrict__ row_ptr,
                                                          int* __restrict__ cursor)
{
    __shared__ int s[1024];
    int t = threadIdx.x;
    int ix = blockIdx.x*1024 + t;
    int v = (ix < NRKEYS) ? cnt[ix] : 0;
    s[t] = v; __syncthreads();
    for (int off=1; off<1024; off<<=1) {
        int u = (t>=off) ? s[t-off] : 0;
        __syncthreads();
        s[t] += u;
        __syncthreads();
    }
    if (ix < NRKEYS) {
        int excl = blockoff[blockIdx.x] + s[t] - v;
        row_ptr[ix] = excl;
        cursor[ix]  = excl;
        if (ix == NRKEYS-1) row_ptr[NRKEYS] = excl + v;
    }
}

__global__ void fill_kernel(const int* __restrict__ ei, const int* __restrict__ et,
                            int* __restrict__ cursor, int* __restrict__ csr_src)
{
    int e = blockIdx.x*256 + threadIdx.x;
    if (e >= E_EDGES) return;
    int src = ei[e];
    int dst = ei[E_EDGES + e];
    int key = dst*R_REL + et[e];
    int pos = atomicAdd(&cursor[key], 1);
    csr_src[pos] = src;
}

// ---------------- weight prep: fp32 sources -> bf16 B^T = [Nout][K] ----------------
__global__ void make_b1t(const float* __restrict__ root1,
                         const float* __restrict__ W1,
                         __hip_bfloat16* __restrict__ B1t)
{
    int idx = blockIdx.x*256 + threadIdx.x;         // n*640 + k
    if (idx >= 256*640) return;
    int n = idx / 640, k = idx % 640;
    float v;
    if (k < 128) v = root1[k*256 + n];
    else         v = W1[(k-128)*256 + n];           // W1 contiguous [R*128][256]
    B1t[idx] = f2bf(v);
}

__global__ void make_b2t(const float* __restrict__ root2,
                         const float* __restrict__ W2,
                         __hip_bfloat16* __restrict__ B2t)
{
    int idx = blockIdx.x*256 + threadIdx.x;         // n*1280 + k
    if (idx >= 256*1280) return;
    int n = idx / 1280, k = idx % 1280;
    float v;
    if (k < 256) v = root2[k*256 + n];
    else         v = W2[(k-256)*256 + n];           // W2 contiguous [R*256][256]
    B2t[idx] = f2bf(v);
}

__global__ void make_b3t(const float* __restrict__ Wq, const float* __restrict__ Wk,
                         const float* __restrict__ Wv, const float* __restrict__ Wsk,
                         const float* __restrict__ bq, const float* __restrict__ bk,
                         const float* __restrict__ bv, const float* __restrict__ bsk,
                         __hip_bfloat16* __restrict__ B3t, float* __restrict__ bias3)
{
    int idx = blockIdx.x*256 + threadIdx.x;         // n*256 + k, n<1024
    if (idx >= 1024*256) return;
    int n = idx / 256, k = idx % 256;
    int g = n >> 8, nn = n & 255;
    const float* W = (g==0)?Wq:(g==1)?Wk:(g==2)?Wv:Wsk;
    B3t[idx] = f2bf(W[k*256 + nn]);
    if (k == 0) {
        const float* B = (g==0)?bq:(g==1)?bk:(g==2)?bv:bsk;
        bias3[n] = B[nn];
    }
}

// generic fp32 -> bf16 elementwise convert (layout-preserving)
__global__ void cvt_f32_bf16(const float* __restrict__ in, __hip_bfloat16* __restrict__ out, int n)
{
    int i = blockIdx.x*256 + threadIdx.x;
    if (i < n) out[i] = f2bf(in[i]);
}

// ---------------- RGCN aggregation (gather, no atomics) ----------------
__global__ __launch_bounds__(128) void agg1_kernel(const float* __restrict__ x,
                                                   const int* __restrict__ row_ptr,
                                                   const int* __restrict__ csr_src,
                                                   __hip_bfloat16* __restrict__ A1)
{
    int b = blockIdx.x;           // i*4 + r
    int i = b >> 2, r = b & 3;
    int f = threadIdx.x;          // 0..127
    int e0 = row_ptr[b], e1 = row_ptr[b+1];
    float s = 0.f;
    for (int e=e0; e<e1; e++) {
        int sidx = csr_src[e];
        s += x[(size_t)sidx*IN_F + f];
    }
    float inv = (e1>e0) ? 1.f/(float)(e1-e0) : 0.f;
    A1[(size_t)i*640 + 128 + r*128 + f] = f2bf(s*inv);
    if (r == 0) A1[(size_t)i*640 + f] = f2bf(x[(size_t)i*IN_F + f]);
}

__global__ __launch_bounds__(256) void agg2_kernel(const int* __restrict__ row_ptr,
                                                   const int* __restrict__ csr_src,
                                                   __hip_bfloat16* __restrict__ A2)
{
    int b = blockIdx.x;
    int i = b >> 2, r = b & 3;
    int f = threadIdx.x;          // 0..255
    int e0 = row_ptr[b], e1 = row_ptr[b+1];
    float s = 0.f;
    for (int e=e0; e<e1; e++) {
        int sidx = csr_src[e];
        s += bf2f(A2[(size_t)sidx*1280 + f]);   // cols 0..255 hold h1
    }
    float inv = (e1>e0) ? 1.f/(float)(e1-e0) : 0.f;
    A2[(size_t)i*1280 + 256 + r*256 + f] = f2bf(s*inv);
}

// ---------------- MFMA GEMM: C[M x Nout] = act(A[M x K] * Bt[Nout x K]^T + bias) ----------------
__global__ __launch_bounds__(256) void gemm_bt(const __hip_bfloat16* __restrict__ A, int lda,
                                               const __hip_bfloat16* __restrict__ Bt,
                                               const float* __restrict__ bias,
                                               __hip_bfloat16* __restrict__ C, int ldc,
                                               int M, int K, int relu)
{
    __shared__ __align__(16) __hip_bfloat16 lds_a[128*32];
    __shared__ __align__(16) __hip_bfloat16 lds_b[128*32];
    const int tid    = threadIdx.x;
    const int tile_m = blockIdx.x * 128;
    const int tile_n = blockIdx.y * 128;
    const int wave   = tid >> 6;
    const int lane   = tid & 63;
    const int wm = wave >> 1, wn = wave & 1;     // 2x2 wave grid: 64x64 each
    const int fm = lane & 15;                    // frag m (A) / n (Bt) / col (C)
    const int q  = lane >> 4;                    // 0..3

    floatx4 acc[4][4];
    #pragma unroll
    for (int i=0;i<4;i++)
        #pragma unroll
        for (int j=0;j<4;j++) acc[i][j] = (floatx4){0.f,0.f,0.f,0.f};

    const int srow   = tid >> 2;                 // 0..63 (plus 64 per pass)
    const int schunk = (tid & 3) * 8;            // element offset along K

    for (int k0 = 0; k0 < K; k0 += 32) {
        __syncthreads();
        #pragma unroll
        for (int p=0;p<2;p++) {
            int row = p*64 + srow;
            int ga  = min(tile_m + row, M-1);    // clamp: pad rows read row M-1 (discarded)
            uint4 v = *(const uint4*)(A + (size_t)ga*lda + k0 + schunk);
            *(uint4*)(&lds_a[row*32 + schunk]) = v;
        }
        #pragma unroll
        for (int p=0;p<2;p++) {
            int row = p*64 + srow;
            uint4 v = *(const uint4*)(Bt + (size_t)(tile_n + row)*K + k0 + schunk);
            *(uint4*)(&lds_b[row*32 + schunk]) = v;
        }
        __syncthreads();

        short8 afr[4], bfr[4];
        #pragma unroll
        for (int i=0;i<4;i++) {
            afr[i] = *(const short8*)(&lds_a[(wm*64 + i*16 + fm)*32 + q*8]);
            bfr[i] = *(const short8*)(&lds_b[(wn*64 + i*16 + fm)*32 + q*8]);
        }
        #pragma unroll
        for (int i=0;i<4;i++)
            #pragma unroll
            for (int j=0;j<4;j++)
                acc[i][j] = __builtin_amdgcn_mfma_f32_16x16x32_bf16(afr[i], bfr[j], acc[i][j], 0,0,0);
    }

    const int crow_base = tile_m + wm*64;
    const int ccol_base = tile_n + wn*64;
    #pragma unroll
    for (int i=0;i<4;i++) {
        #pragma unroll
        for (int j=0;j<4;j++) {
            int c  = ccol_base + j*16 + fm;
            float bb = bias[c];
            #pragma unroll
            for (int rg=0; rg<4; rg++) {
                int r = crow_base + i*16 + q*4 + rg;
                if (r < M) {
                    float v = acc[i][j][rg] + bb;
                    if (relu) v = fmaxf(v, 0.f);
                    C[(size_t)r*ldc + c] = f2bf(v);
                }
            }
        }
    }
}

// ---------------- TransformerConv attention (one block/node, one wave/head) ----------------
__global__ __launch_bounds__(256) void attn_kernel(const __hip_bfloat16* __restrict__ qkvs,
                                                   const int* __restrict__ row_ptr,
                                                   const int* __restrict__ csr_src,
                                                   __hip_bfloat16* __restrict__ hatt)
{
    int i = blockIdx.x;
    int h = threadIdx.x >> 6;
    int l = threadIdx.x & 63;
    const __hip_bfloat16* qrow = qkvs + (size_t)i*1024;
    float ql = bf2f(qrow[h*64 + l]);
    int e0 = row_ptr[i*R_REL], e1 = row_ptr[i*R_REL + R_REL];
    float m = -1e30f, ssum = 0.f, acc = 0.f;
    for (int e=e0; e<e1; e++) {
        int s = csr_src[e];
        const __hip_bfloat16* kv = qkvs + (size_t)s*1024;
        float kl = bf2f(kv[256 + h*64 + l]);
        float d = ql*kl;
        #pragma unroll
        for (int o=32;o>0;o>>=1) d += __shfl_xor(d, o, 64);
        float sc = d * 0.125f;                 // 1/sqrt(64)
        float mn = fmaxf(m, sc);
        float corr = __expf(m - mn);
        float p    = __expf(sc - mn);
        ssum = ssum*corr + p;
        float vl = bf2f(kv[512 + h*64 + l]);
        acc = acc*corr + p*vl;
        m = mn;
    }
    float o = acc / fmaxf(ssum, 1e-16f);
    float skip = bf2f(qrow[768 + h*64 + l]);
    hatt[(size_t)i*256 + h*64 + l] = f2bf(o + skip);
}

// ---------------- GRU elementwise (bf16 gates, fp32 math, fp32 out) ----------------
__global__ void gru_kernel(const __hip_bfloat16* __restrict__ gi,
                           const __hip_bfloat16* __restrict__ gh,
                           const float* __restrict__ hprev,
                           float* __restrict__ out)
{
    int idx = blockIdx.x*256 + threadIdx.x;
    if (idx >= N_NODES*HIDF) return;
    int i = idx / HIDF, c = idx % HIDF;
    size_t gb = (size_t)i*768;
    float ir = bf2f(gi[gb + c]), iz = bf2f(gi[gb + 256 + c]), in = bf2f(gi[gb + 512 + c]);
    float hr = bf2f(gh[gb + c]), hz = bf2f(gh[gb + 256 + c]), hn = bf2f(gh[gb + 512 + c]);
    float r = 1.f/(1.f + __expf(-(ir+hr)));
    float z = 1.f/(1.f + __expf(-(iz+hz)));
    float n = tanhf(in + r*hn);
    float h = hprev[idx];
    out[idx] = (1.f - z)*n + z*h;
}

// ---------------- launch ----------------
// Inputs fp32 (verified round 3); bf16 internally for MFMA. Workspace ~96 MB:
//   P1 (30.72 MB): A1 -> h2 -> hatt -> gh
//   P2 (51.2  MB): A2 -> qkvs -> gi
// Ordering: gemm4 (reads hatt, writes gi) BEFORE gemm5 (writes gh over hatt).
extern "C" void kernel_launch(void* const* d_in, const int* in_sizes, int n_in,
                              void* d_out, int out_size, void* d_ws, size_t ws_size,
                              hipStream_t stream)
{
    const float* x       = (const float*)d_in[0];
    const int* edge_index= (const int*)d_in[1];
    const int* edge_type = (const int*)d_in[2];
    const float* hprev   = (const float*)d_in[3];
    const float* W1      = (const float*)d_in[4];
    const float* root1   = (const float*)d_in[5];
    const float* b1      = (const float*)d_in[6];
    const float* W2      = (const float*)d_in[7];
    const float* root2   = (const float*)d_in[8];
    const float* b2      = (const float*)d_in[9];
    const float* Wq      = (const float*)d_in[10];
    const float* bq      = (const float*)d_in[11];
    const float* Wk      = (const float*)d_in[12];
    const float* bk      = (const float*)d_in[13];
    const float* Wv      = (const float*)d_in[14];
    const float* bv      = (const float*)d_in[15];
    const float* Wskip   = (const float*)d_in[16];
    const float* bskip   = (const float*)d_in[17];
    const float* W_ih    = (const float*)d_in[18];
    const float* b_ih    = (const float*)d_in[19];
    const float* W_hh    = (const float*)d_in[20];
    const float* b_hh    = (const float*)d_in[21];

    char* ws = (char*)d_ws;
    size_t off = 0;
    auto take = [&](size_t bytes)->char* {
        char* p = ws + off;
        off = (off + bytes + 255) & ~(size_t)255;
        return p;
    };
    int* cnt        = (int*)take((size_t)NRKEYS*4);
    int* row_ptr    = (int*)take((size_t)(NRKEYS+1)*4);
    int* cursor     = (int*)take((size_t)NRKEYS*4);
    int* csr_src    = (int*)take((size_t)E_EDGES*4);
    int* blocksum   = (int*)take((size_t)SCAN_BLOCKS*4);
    int* blockoff   = (int*)take((size_t)(SCAN_BLOCKS+1)*4);
    __hip_bfloat16* B1t   = (__hip_bfloat16*)take((size_t)256*640*2);
    __hip_bfloat16* B2t   = (__hip_bfloat16*)take((size_t)256*1280*2);
    __hip_bfloat16* B3t   = (__hip_bfloat16*)take((size_t)1024*256*2);
    __hip_bfloat16* Biht  = (__hip_bfloat16*)take((size_t)768*256*2);
    __hip_bfloat16* Bhht  = (__hip_bfloat16*)take((size_t)768*256*2);
    float*          bias3 = (float*)take((size_t)1024*4);
    __hip_bfloat16* hprev_bf = (__hip_bfloat16*)take((size_t)N_NODES*256*2);
    // P1: max(A1 N*640, h2 N*256, hatt N*256, gh N*768) bf16
    char* P1 = take((size_t)N_NODES*768*2);
    // P2: max(A2 N*1280, qkvs N*1024, gi N*768) bf16
    char* P2 = take((size_t)N_NODES*1280*2);

    __hip_bfloat16* A1   = (__hip_bfloat16*)P1;   // [N,640]  dead after gemm1
    __hip_bfloat16* h2   = (__hip_bfloat16*)P1;   // [N,256]  dead after gemm3
    __hip_bfloat16* hatt = (__hip_bfloat16*)P1;   // [N,256]  dead after gemm4
    __hip_bfloat16* gh   = (__hip_bfloat16*)P1;   // [N,768]  written gemm5
    __hip_bfloat16* A2   = (__hip_bfloat16*)P2;   // [N,1280] dead after gemm2
    __hip_bfloat16* qkvs = (__hip_bfloat16*)P2;   // [N,1024] dead after attn
    __hip_bfloat16* gi   = (__hip_bfloat16*)P2;   // [N,768]  written gemm4

    hipMemsetAsync(cnt, 0, (size_t)NRKEYS*4, stream);
    count_kernel<<<(E_EDGES+255)/256, 256, 0, stream>>>(edge_index, edge_type, cnt);
    scan_reduce_kernel<<<SCAN_BLOCKS, 1024, 0, stream>>>(cnt, blocksum);
    scan_sums_kernel<<<1, 128, 0, stream>>>(blocksum, blockoff);
    scan_apply_kernel<<<SCAN_BLOCKS, 1024, 0, stream>>>(cnt, blockoff, row_ptr, cursor);
    fill_kernel<<<(E_EDGES+255)/256, 256, 0, stream>>>(edge_index, edge_type, cursor, csr_src);

    make_b1t<<<(256*640+255)/256, 256, 0, stream>>>(root1, W1, B1t);
    make_b2t<<<(256*1280+255)/256, 256, 0, stream>>>(root2, W2, B2t);
    make_b3t<<<(1024*256+255)/256, 256, 0, stream>>>(Wq, Wk, Wv, Wskip, bq, bk, bv, bskip, B3t, bias3);
    cvt_f32_bf16<<<(768*256+255)/256, 256, 0, stream>>>(W_ih, Biht, 768*256);
    cvt_f32_bf16<<<(768*256+255)/256, 256, 0, stream>>>(W_hh, Bhht, 768*256);
    cvt_f32_bf16<<<(N_NODES*256+255)/256, 256, 0, stream>>>(hprev, hprev_bf, N_NODES*256);

    agg1_kernel<<<NRKEYS, 128, 0, stream>>>(x, row_ptr, csr_src, A1);

    dim3 g12(157, 2);
    // h1 = relu(A1 * B1) written into A2 cols 0..255 (ldc=1280)
    gemm_bt<<<g12, 256, 0, stream>>>(A1, 640, B1t, b1, A2, 1280, N_NODES, 640, 1);

    agg2_kernel<<<NRKEYS, 256, 0, stream>>>(row_ptr, csr_src, A2);

    // h2 overwrites A1 (dead) in P1
    gemm_bt<<<g12, 256, 0, stream>>>(A2, 1280, B2t, b2, h2, 256, N_NODES, 1280, 1);

    // qkvs overwrites A2 (dead) in P2
    dim3 g3(157, 8);
    gemm_bt<<<g3, 256, 0, stream>>>(h2, 256, B3t, bias3, qkvs, 1024, N_NODES, 256, 0);

    // hatt overwrites h2 (dead) in P1
    attn_kernel<<<N_NODES, 256, 0, stream>>>(qkvs, row_ptr, csr_src, hatt);

    dim3 g45(157, 6);
    // gi overwrites qkvs (dead) in P2 -- must run before gemm5
    gemm_bt<<<g45, 256, 0, stream>>>(hatt,     256, Biht, b_ih, gi, 768, N_NODES, 256, 0);
    // gh overwrites hatt (dead) in P1
    gemm_bt<<<g45, 256, 0, stream>>>(hprev_bf, 256, Bhht, b_hh, gh, 768, N_NODES, 256, 0);

    gru_kernel<<<(N_NODES*HIDF+255)/256, 256, 0, stream>>>(gi, gh, hprev, (float*)d_out);
}